// Round 1
// 718.861 us; speedup vs baseline: 1.2453x; 1.2453x over previous
//
#include <hip/hip_runtime.h>

// Problem constants
#define B_ 16
#define N_ 8192
#define C_ 128
#define NC_ 1048576          // N_*C_
#define NE_ 16777216         // B_*N_*C_

typedef unsigned short u16;
typedef unsigned int u32;
typedef __bf16 bf16x8 __attribute__((ext_vector_type(8)));
typedef float f32x4 __attribute__((ext_vector_type(4)));

__device__ __forceinline__ u16 f2bf(float x){
  u32 u = __float_as_uint(x);
  u32 r = (u + 0x7fffu + ((u >> 16) & 1u)) >> 16;   // RNE
  return (u16)r;
}
__device__ __forceinline__ float bf2f(u16 h){ return __uint_as_float(((u32)h) << 16); }

// ---------------- init: zero accumulators + misc ints + nsq ----------------
__global__ void k_init(float* __restrict__ ws){
  int i = blockIdx.x*256 + threadIdx.x;
  if (i < 8224) ws[i] = 0.f;
}

// ---------------- sort: rank-by-counting descending argsort (stable) -------
// v2: one WAVE per element (was one thread) -> 4096 blocks instead of 64.
// Each block stages the 32KB key row in LDS (5 blocks/CU fit), each lane
// scans 128 keys, wave shfl-reduce yields the rank.
__global__ __launch_bounds__(256) void k_sort(const float* __restrict__ gt,
                                              int* __restrict__ order,
                                              int* __restrict__ misc){
  __shared__ __align__(16) float keys[N_];
  __shared__ int cw[4];
  const int row = blockIdx.x >> 11;            // 2048 blocks per row
  const int blk = blockIdx.x & 2047;
  const float4* g4 = (const float4*)(gt + row*N_);
  float4* k4s = (float4*)keys;
  #pragma unroll
  for (int k = 0; k < 8; ++k) k4s[threadIdx.x + k*256] = g4[threadIdx.x + k*256];
  __syncthreads();
  const int w = threadIdx.x >> 6, lane = threadIdx.x & 63;
  const int i = blk*4 + w;                     // element owned by this wave
  const float ki = keys[i];
  int rank = 0;
  #pragma unroll 8
  for (int it = 0; it < 32; ++it){
    const int j4 = lane + it*64;
    float4 kv = k4s[j4];
    const int j = j4*4;
    rank += (kv.x > ki) || ((kv.x == ki) && (j     < i));
    rank += (kv.y > ki) || ((kv.y == ki) && (j + 1 < i));
    rank += (kv.z > ki) || ((kv.z == ki) && (j + 2 < i));
    rank += (kv.w > ki) || ((kv.w == ki) && (j + 3 < i));
  }
  #pragma unroll
  for (int o = 32; o; o >>= 1) rank += __shfl_down(rank, o);
  if (lane == 0) order[row*N_ + rank] = i;
  // positive count: one block per row does it from LDS, direct store
  if (blk == 0){
    int cnt = 0;
    #pragma unroll
    for (int k = 0; k < 8; ++k){
      float4 v = k4s[threadIdx.x + k*256];
      cnt += (v.x > 0.f) + (v.y > 0.f) + (v.z > 0.f) + (v.w > 0.f);
    }
    #pragma unroll
    for (int o = 32; o; o >>= 1) cnt += __shfl_down(cnt, o);
    if (lane == 0) cw[w] = cnt;
    __syncthreads();
    if (threadIdx.x == 0) misc[row] = cw[0]+cw[1]+cw[2]+cw[3];
  }
}

__global__ void k_index(int* __restrict__ misc){
  int s0 = misc[0]; if (s0 <= 0) s0 = N_;
  int s1 = misc[1]; if (s1 <= 0) s1 = N_;
  misc[2] = (s0 < s1) ? s0 : s1;
}

// ---------------- gnn: gathered cosine-embedding loss ----------------------
__global__ __launch_bounds__(256) void k_gnn(const float* __restrict__ sep,
                                             const int* __restrict__ order,
                                             const int* __restrict__ misc,
                                             float* __restrict__ acc){
  const int gw   = (blockIdx.x*256 + threadIdx.x) >> 6;   // 0..8191
  const int lane = threadIdx.x & 63;
  const int i0 = order[gw], i1 = order[N_ + gw];
  const float2* r0 = (const float2*)(sep + (size_t)i0*C_);
  const float2* r1 = (const float2*)(sep + (size_t)NC_ + (size_t)i1*C_);
  float2 a = r0[lane], b = r1[lane];
  float dot = a.x*b.x + a.y*b.y;
  float n0  = a.x*a.x + a.y*a.y;
  float n1  = b.x*b.x + b.y*b.y;
  for (int o = 32; o; o >>= 1){
    dot += __shfl_down(dot, o);
    n0  += __shfl_down(n0, o);
    n1  += __shfl_down(n1, o);
  }
  if (lane == 0 && gw < misc[2]){
    float cs = dot / (fmaxf(sqrtf(n0), 1e-8f) * fmaxf(sqrtf(n1), 1e-8f));
    atomicAdd(&acc[0], 1.f - cs);
  }
}

// ---------------- pearson: first 16 flattened rows only --------------------
__global__ __launch_bounds__(1024) void k_pearson(const float* __restrict__ x,
                                                  const float* __restrict__ y,
                                                  float* __restrict__ acc){
  const int r = threadIdx.x >> 6, lane = threadIdx.x & 63;
  const float2* xr = (const float2*)(x + r*C_);
  const float2* yr = (const float2*)(y + r*C_);
  float2 a = xr[lane], b = yr[lane];
  float sx = a.x + a.y, sy = b.x + b.y;
  float sxx = a.x*a.x + a.y*a.y;
  float syy = b.x*b.x + b.y*b.y;
  float sxy = a.x*b.x + a.y*b.y;
  for (int o = 32; o; o >>= 1){
    sx += __shfl_down(sx, o); sy += __shfl_down(sy, o);
    sxx += __shfl_down(sxx, o); syy += __shfl_down(syy, o);
    sxy += __shfl_down(sxy, o);
  }
  if (lane == 0){
    const float invn = 1.f/128.f;
    float num = sxy - sx*sy*invn;
    float vx  = sxx - sx*sx*invn;
    float vy  = syy - sy*sy*invn;
    float den = sqrtf(vx*vy);
    float rp  = (den == 0.f) ? 0.f : num/den;
    atomicAdd(&acc[1], 1.f - rp);
  }
}

// ---------------- recon: sum of squared diffs over both pairs --------------
__global__ __launch_bounds__(256) void k_recon(const float4* __restrict__ a0, const float4* __restrict__ b0,
                                               const float4* __restrict__ a1, const float4* __restrict__ b1,
                                               float* __restrict__ acc){
  __shared__ float sw[4];
  const unsigned NE4 = NE_/4;
  float s = 0.f;
  for (unsigned i = blockIdx.x*256u + threadIdx.x; i < 2u*NE4; i += gridDim.x*256u){
    float4 x, y;
    if (i < NE4){ x = a0[i]; y = b0[i]; }
    else        { x = a1[i - NE4]; y = b1[i - NE4]; }
    float dx = x.x - y.x, dy = x.y - y.y, dz = x.z - y.z, dw = x.w - y.w;
    s += dx*dx + dy*dy + dz*dz + dw*dw;
  }
  for (int o = 32; o; o >>= 1) s += __shfl_down(s, o);
  if ((threadIdx.x & 63) == 0) sw[threadIdx.x >> 6] = s;
  __syncthreads();
  if (threadIdx.x == 0) atomicAdd(&acc[2], sw[0]+sw[1]+sw[2]+sw[3]);
}

// ---------------- means over batch (bf16 output) ---------------------------
__global__ __launch_bounds__(256) void k_mean(const float4* __restrict__ t0, const float4* __restrict__ t1,
                                              const float4* __restrict__ t2, const float4* __restrict__ t3,
                                              u16* __restrict__ M){
  const int which = blockIdx.x >> 10;
  const int i = (blockIdx.x & 1023)*256 + threadIdx.x;   // float4 index < NC_/4
  const float4* src = (which == 0) ? t0 : (which == 1) ? t1 : (which == 2) ? t2 : t3;
  float4 s = {0.f, 0.f, 0.f, 0.f};
  #pragma unroll
  for (int b = 0; b < B_; ++b){
    float4 v = src[(size_t)b*(NC_/4) + i];
    s.x += v.x; s.y += v.y; s.z += v.z; s.w += v.w;
  }
  ushort4 o;
  o.x = f2bf(s.x*0.0625f); o.y = f2bf(s.y*0.0625f);
  o.z = f2bf(s.z*0.0625f); o.w = f2bf(s.w*0.0625f);
  *(ushort4*)(M + (size_t)which*NC_ + 4*(size_t)i) = o;
}

// ---------------- centered GEMM via MFMA bf16 + norm partials --------------
// block = (loss, b, kchunk); computes partial corr[128][128] over 1024 rows.
constexpr int LDK = 40;   // padded row stride (u16) -> 80B rows, 16B-aligned frags
__global__ __launch_bounds__(256) void k_gemm(const float* __restrict__ hs, const float* __restrict__ hp,
                                              const float* __restrict__ ls, const float* __restrict__ lp,
                                              const u16* __restrict__ M, float* __restrict__ slab,
                                              float* __restrict__ nsq){
  __shared__ __align__(16) u16 PT[128*LDK];
  __shared__ __align__(16) u16 ST[128*LDK];
  const int bid = blockIdx.x;
  const int loss = bid >> 7, b = (bid >> 3) & 15, ch = bid & 7;
  const float* __restrict__ p = loss ? ls : hs;
  const float* __restrict__ s = loss ? lp : hp;
  const u16* __restrict__ Mp = M + (size_t)(loss ? 2 : 0)*NC_;
  const u16* __restrict__ Ms = M + (size_t)(loss ? 3 : 1)*NC_;
  const int t = threadIdx.x;
  const int c = t & 127;
  const int w = t >> 6, lane = t & 63, m = lane & 15, q = lane >> 4;
  const int n0 = ch * 1024;
  const size_t bOff = (size_t)b*NC_;
  float nsp = 0.f, nss = 0.f;
  f32x4 acc[2][8];
  #pragma unroll
  for (int i = 0; i < 2; ++i)
    #pragma unroll
    for (int j = 0; j < 8; ++j) acc[i][j] = 0.f;
  u32* PT32 = (u32*)PT;
  u32* ST32 = (u32*)ST;

  for (int st = 0; st < 32; ++st){
    const int row0 = n0 + st*32;
    #pragma unroll
    for (int it = 0; it < 8; ++it){
      const int idx = it*256 + t;
      const int k2 = idx >> 7;                 // 0..15, c stays t&127
      const int r = row0 + 2*k2;
      const size_t g = bOff + (size_t)r*C_ + c;
      const int mo = r*C_ + c;
      float v0 = p[g]       - bf2f(Mp[mo]);
      float v1 = p[g + C_]  - bf2f(Mp[mo + C_]);
      nsp += v0*v0 + v1*v1;
      PT32[c*(LDK/2) + k2] = (u32)f2bf(v0) | ((u32)f2bf(v1) << 16);
      float u0 = s[g]       - bf2f(Ms[mo]);
      float u1 = s[g + C_]  - bf2f(Ms[mo + C_]);
      nss += u0*u0 + u1*u1;
      ST32[c*(LDK/2) + k2] = (u32)f2bf(u0) | ((u32)f2bf(u1) << 16);
    }
    __syncthreads();
    // A[m][k] = centered p (c-major), B[k][n] = centered s; D = A*B
    bf16x8 a0 = *(const bf16x8*)(PT + ((2*w + 0)*16 + m)*LDK + 8*q);
    bf16x8 a1 = *(const bf16x8*)(PT + ((2*w + 1)*16 + m)*LDK + 8*q);
    #pragma unroll
    for (int j = 0; j < 8; ++j){
      bf16x8 bb = *(const bf16x8*)(ST + (j*16 + m)*LDK + 8*q);
      acc[0][j] = __builtin_amdgcn_mfma_f32_16x16x32_bf16(a0, bb, acc[0][j], 0, 0, 0);
      acc[1][j] = __builtin_amdgcn_mfma_f32_16x16x32_bf16(a1, bb, acc[1][j], 0, 0, 0);
    }
    __syncthreads();
  }

  float* out = slab + (size_t)bid*16384;
  #pragma unroll
  for (int i = 0; i < 2; ++i)
    #pragma unroll
    for (int j = 0; j < 8; ++j){
      const int rowB = (2*w + i)*16 + 4*q;     // C/D: row=(lane>>4)*4+reg
      const int colB = j*16 + m;               //       col=lane&15
      #pragma unroll
      for (int r2 = 0; r2 < 4; ++r2)
        out[(rowB + r2)*C_ + colB] = acc[i][j][r2];
    }
  atomicAdd(&nsq[(loss*2 + 0)*2048 + b*C_ + c], nsp);
  atomicAdd(&nsq[(loss*2 + 1)*2048 + b*C_ + c], nss);
}

// ---------------- reduce slabs -> sum of corr^2 ----------------------------
__global__ __launch_bounds__(256) void k_diffred(const float* __restrict__ slab,
                                                 const float* __restrict__ nsq,
                                                 float* __restrict__ acc){
  __shared__ float sw[4];
  const int e = blockIdx.x*256 + threadIdx.x;    // < 524288
  const int loss = e >> 18;
  const int rem = e & 262143;
  const int b = rem >> 14;
  const int cd = rem & 16383;
  const int cc = cd >> 7, dd = cd & 127;
  float A = 0.f;
  const size_t base = (size_t)((loss*16 + b)*8)*16384 + cd;
  #pragma unroll
  for (int chn = 0; chn < 8; ++chn) A += slab[base + (size_t)chn*16384];
  float np_ = sqrtf(nsq[(loss*2 + 0)*2048 + b*C_ + cc]);
  float ns_ = sqrtf(nsq[(loss*2 + 1)*2048 + b*C_ + dd]);
  float corr = A / (fmaxf(np_, 1e-12f) * fmaxf(ns_, 1e-12f));
  float v = corr*corr;
  for (int o = 32; o; o >>= 1) v += __shfl_down(v, o);
  if ((threadIdx.x & 63) == 0) sw[threadIdx.x >> 6] = v;
  __syncthreads();
  if (threadIdx.x == 0) atomicAdd(&acc[3], sw[0]+sw[1]+sw[2]+sw[3]);
}

// ---------------- final composition ----------------------------------------
__global__ void k_final(const float* __restrict__ acc, const int* __restrict__ misc,
                        float* __restrict__ out){
  // 2*pearson_mean + (diff2+diff3) + 0.05*(recon_hf+recon_lf) + gnn
  out[0] = 2.0f*(acc[1]*(1.f/16.f))
         + acc[3]*(1.f/262144.f)
         + 0.05f*(acc[2]*(1.f/16777216.f))
         + acc[0]/(float)misc[2];
}

extern "C" void kernel_launch(void* const* d_in, const int* in_sizes, int n_in,
                              void* d_out, int out_size, void* d_ws, size_t ws_size,
                              hipStream_t stream){
  const float* hf  = (const float*)d_in[0];
  const float* lf  = (const float*)d_in[1];
  const float* hs  = (const float*)d_in[2];   // hf_shared
  const float* lsh = (const float*)d_in[3];   // lf_shared
  const float* hp  = (const float*)d_in[4];   // hf_private
  const float* lp  = (const float*)d_in[5];   // lf_private
  const float* rhf = (const float*)d_in[6];
  const float* rlf = (const float*)d_in[7];
  const float* sep = (const float*)d_in[8];
  // d_in[9] = noi_node: provably contributes 0 (mean-centering over batch of 1)
  const float* gt  = (const float*)d_in[10];

  // ws layout (float units). Total ~25.3 MB.
  float* ws    = (float*)d_ws;
  float* acc   = ws;                        // [0..16): gnn, pearson, recon, diff
  int*   misc  = (int*)(ws + 16);           // [16..32): pos0, pos1, index
  float* nsq   = ws + 32;                   // 4*16*128 = 8192 floats
  int*   order = (int*)(ws + 8224);         // 2*8192 ints
  u16*   M     = (u16*)(ws + 24608);        // 4*NC_ u16 (bf16 means)
  float* slab  = ws + 2121760;              // 256*16384 floats (GEMM partials)

  k_init<<<33, 256, 0, stream>>>(ws);
  k_sort<<<4096, 256, 0, stream>>>(gt, order, misc);
  k_index<<<1, 1, 0, stream>>>(misc);
  k_gnn<<<2048, 256, 0, stream>>>(sep, order, misc, acc);
  k_pearson<<<1, 1024, 0, stream>>>(hs, lsh, acc);
  k_recon<<<4096, 256, 0, stream>>>((const float4*)rhf, (const float4*)hf,
                                    (const float4*)rlf, (const float4*)lf, acc);
  k_mean<<<4096, 256, 0, stream>>>((const float4*)hs, (const float4*)hp,
                                   (const float4*)lsh, (const float4*)lp, M);
  k_gemm<<<256, 256, 0, stream>>>(hs, hp, lsh, lp, M, slab, nsq);
  k_diffred<<<2048, 256, 0, stream>>>(slab, nsq, acc);
  k_final<<<1, 1, 0, stream>>>(acc, misc, (float*)d_out);
}

// Round 4
// 698.774 us; speedup vs baseline: 1.2811x; 1.0287x over previous
//
// v3 resubmit: identical algorithm to v2 (two infra failures, no kernel verdict);
// comment bump only to avoid any stale-artifact caching by source hash.
#include <hip/hip_runtime.h>

// Problem constants
#define B_ 16
#define N_ 8192
#define C_ 128
#define NC_ 1048576          // N_*C_
#define NE_ 16777216         // B_*N_*C_

typedef unsigned short u16;
typedef unsigned int u32;
typedef __bf16 bf16x8 __attribute__((ext_vector_type(8)));
typedef float f32x4 __attribute__((ext_vector_type(4)));

__device__ __forceinline__ u16 f2bf(float x){
  u32 u = __float_as_uint(x);
  u32 r = (u + 0x7fffu + ((u >> 16) & 1u)) >> 16;   // RNE
  return (u16)r;
}
__device__ __forceinline__ float bf2f(u16 h){ return __uint_as_float(((u32)h) << 16); }

// ---------------- init: zero accumulators + misc ints + nsq ----------------
__global__ void k_init(float* __restrict__ ws){
  int i = blockIdx.x*256 + threadIdx.x;
  if (i < 8224) ws[i] = 0.f;
}

// ---------------- sort: rank-by-counting descending argsort (stable) -------
// one WAVE per element; block stages the 32KB key row in LDS.
__global__ __launch_bounds__(256) void k_sort(const float* __restrict__ gt,
                                              int* __restrict__ order,
                                              int* __restrict__ misc){
  __shared__ __align__(16) float keys[N_];
  __shared__ int cw[4];
  const int row = blockIdx.x >> 11;            // 2048 blocks per row
  const int blk = blockIdx.x & 2047;
  const float4* g4 = (const float4*)(gt + row*N_);
  float4* k4s = (float4*)keys;
  #pragma unroll
  for (int k = 0; k < 8; ++k) k4s[threadIdx.x + k*256] = g4[threadIdx.x + k*256];
  __syncthreads();
  const int w = threadIdx.x >> 6, lane = threadIdx.x & 63;
  const int i = blk*4 + w;                     // element owned by this wave
  const float ki = keys[i];
  int rank = 0;
  #pragma unroll 8
  for (int it = 0; it < 32; ++it){
    const int j4 = lane + it*64;
    float4 kv = k4s[j4];
    const int j = j4*4;
    rank += (kv.x > ki) || ((kv.x == ki) && (j     < i));
    rank += (kv.y > ki) || ((kv.y == ki) && (j + 1 < i));
    rank += (kv.z > ki) || ((kv.z == ki) && (j + 2 < i));
    rank += (kv.w > ki) || ((kv.w == ki) && (j + 3 < i));
  }
  #pragma unroll
  for (int o = 32; o; o >>= 1) rank += __shfl_down(rank, o);
  if (lane == 0) order[row*N_ + rank] = i;
  // positive count: one block per row does it from LDS, direct store
  if (blk == 0){
    int cnt = 0;
    #pragma unroll
    for (int k = 0; k < 8; ++k){
      float4 v = k4s[threadIdx.x + k*256];
      cnt += (v.x > 0.f) + (v.y > 0.f) + (v.z > 0.f) + (v.w > 0.f);
    }
    #pragma unroll
    for (int o = 32; o; o >>= 1) cnt += __shfl_down(cnt, o);
    if (lane == 0) cw[w] = cnt;
    __syncthreads();
    if (threadIdx.x == 0) misc[row] = cw[0]+cw[1]+cw[2]+cw[3];
  }
}

__global__ void k_index(int* __restrict__ misc){
  int s0 = misc[0]; if (s0 <= 0) s0 = N_;
  int s1 = misc[1]; if (s1 <= 0) s1 = N_;
  misc[2] = (s0 < s1) ? s0 : s1;
}

// ---------------- gnn: gathered cosine-embedding loss ----------------------
__global__ __launch_bounds__(256) void k_gnn(const float* __restrict__ sep,
                                             const int* __restrict__ order,
                                             const int* __restrict__ misc,
                                             float* __restrict__ acc){
  const int gw   = (blockIdx.x*256 + threadIdx.x) >> 6;   // 0..8191
  const int lane = threadIdx.x & 63;
  const int i0 = order[gw], i1 = order[N_ + gw];
  const float2* r0 = (const float2*)(sep + (size_t)i0*C_);
  const float2* r1 = (const float2*)(sep + (size_t)NC_ + (size_t)i1*C_);
  float2 a = r0[lane], b = r1[lane];
  float dot = a.x*b.x + a.y*b.y;
  float n0  = a.x*a.x + a.y*a.y;
  float n1  = b.x*b.x + b.y*b.y;
  for (int o = 32; o; o >>= 1){
    dot += __shfl_down(dot, o);
    n0  += __shfl_down(n0, o);
    n1  += __shfl_down(n1, o);
  }
  if (lane == 0 && gw < misc[2]){
    float cs = dot / (fmaxf(sqrtf(n0), 1e-8f) * fmaxf(sqrtf(n1), 1e-8f));
    atomicAdd(&acc[0], 1.f - cs);
  }
}

// ---------------- pearson: first 16 flattened rows only --------------------
__global__ __launch_bounds__(1024) void k_pearson(const float* __restrict__ x,
                                                  const float* __restrict__ y,
                                                  float* __restrict__ acc){
  const int r = threadIdx.x >> 6, lane = threadIdx.x & 63;
  const float2* xr = (const float2*)(x + r*C_);
  const float2* yr = (const float2*)(y + r*C_);
  float2 a = xr[lane], b = yr[lane];
  float sx = a.x + a.y, sy = b.x + b.y;
  float sxx = a.x*a.x + a.y*a.y;
  float syy = b.x*b.x + b.y*b.y;
  float sxy = a.x*b.x + a.y*b.y;
  for (int o = 32; o; o >>= 1){
    sx += __shfl_down(sx, o); sy += __shfl_down(sy, o);
    sxx += __shfl_down(sxx, o); syy += __shfl_down(syy, o);
    sxy += __shfl_down(sxy, o);
  }
  if (lane == 0){
    const float invn = 1.f/128.f;
    float num = sxy - sx*sy*invn;
    float vx  = sxx - sx*sx*invn;
    float vy  = syy - sy*sy*invn;
    float den = sqrtf(vx*vy);
    float rp  = (den == 0.f) ? 0.f : num/den;
    atomicAdd(&acc[1], 1.f - rp);
  }
}

// ---------------- recon: sum of squared diffs over both pairs --------------
// branch-free block->pair mapping, 8 fully-unrolled independent float4
// loads per tensor (256B in flight per thread) for max MLP.
__global__ __launch_bounds__(256) void k_recon(const float4* __restrict__ a0, const float4* __restrict__ b0,
                                               const float4* __restrict__ a1, const float4* __restrict__ b1,
                                               float* __restrict__ acc){
  __shared__ float sw[4];
  const int pair = blockIdx.x >> 11;               // 0..1
  const unsigned blk = blockIdx.x & 2047;
  const float4* __restrict__ x = pair ? a1 : a0;
  const float4* __restrict__ y = pair ? b1 : b0;
  const unsigned base = blk*256u + threadIdx.x;    // < 524288
  const unsigned STR = 524288u;                    // 2048 blocks * 256 thr
  float4 xv[8], yv[8];
  #pragma unroll
  for (int k = 0; k < 8; ++k){ xv[k] = x[base + k*STR]; yv[k] = y[base + k*STR]; }
  float s = 0.f;
  #pragma unroll
  for (int k = 0; k < 8; ++k){
    float dx = xv[k].x - yv[k].x, dy = xv[k].y - yv[k].y;
    float dz = xv[k].z - yv[k].z, dw = xv[k].w - yv[k].w;
    s += dx*dx + dy*dy + dz*dz + dw*dw;
  }
  for (int o = 32; o; o >>= 1) s += __shfl_down(s, o);
  if ((threadIdx.x & 63) == 0) sw[threadIdx.x >> 6] = s;
  __syncthreads();
  if (threadIdx.x == 0) atomicAdd(&acc[2], sw[0]+sw[1]+sw[2]+sw[3]);
}

// ---------------- means over batch (bf16 output) ---------------------------
// 2 float4 columns per thread -> 32 independent loads in flight.
__global__ __launch_bounds__(256) void k_mean(const float4* __restrict__ t0, const float4* __restrict__ t1,
                                              const float4* __restrict__ t2, const float4* __restrict__ t3,
                                              u16* __restrict__ M){
  const int which = blockIdx.x >> 9;                     // 4 tensors x 512 blocks
  const int i0 = (blockIdx.x & 511)*512 + threadIdx.x;   // col pair: i0, i0+256
  const float4* src = (which == 0) ? t0 : (which == 1) ? t1 : (which == 2) ? t2 : t3;
  float4 s0 = {0.f,0.f,0.f,0.f}, s1 = {0.f,0.f,0.f,0.f};
  #pragma unroll
  for (int b = 0; b < B_; ++b){
    float4 v0 = src[(size_t)b*(NC_/4) + i0];
    float4 v1 = src[(size_t)b*(NC_/4) + i0 + 256];
    s0.x += v0.x; s0.y += v0.y; s0.z += v0.z; s0.w += v0.w;
    s1.x += v1.x; s1.y += v1.y; s1.z += v1.z; s1.w += v1.w;
  }
  ushort4 o0, o1;
  o0.x = f2bf(s0.x*0.0625f); o0.y = f2bf(s0.y*0.0625f);
  o0.z = f2bf(s0.z*0.0625f); o0.w = f2bf(s0.w*0.0625f);
  o1.x = f2bf(s1.x*0.0625f); o1.y = f2bf(s1.y*0.0625f);
  o1.z = f2bf(s1.z*0.0625f); o1.w = f2bf(s1.w*0.0625f);
  *(ushort4*)(M + (size_t)which*NC_ + 4*(size_t)i0)         = o0;
  *(ushort4*)(M + (size_t)which*NC_ + 4*(size_t)(i0 + 256)) = o1;
}

// ---------------- centered GEMM via MFMA bf16 + norm partials --------------
// 512-thread blocks (8 waves/CU instead of 4). Each wave owns one 16-row
// m-tile; staging work per thread halved. Same grid/slab/math as before.
constexpr int LDK = 40;   // padded row stride (u16) -> 80B rows, 16B-aligned frags
__global__ __launch_bounds__(512) void k_gemm(const float* __restrict__ hs, const float* __restrict__ hp,
                                              const float* __restrict__ ls, const float* __restrict__ lp,
                                              const u16* __restrict__ M, float* __restrict__ slab,
                                              float* __restrict__ nsq){
  __shared__ __align__(16) u16 PT[128*LDK];
  __shared__ __align__(16) u16 ST[128*LDK];
  const int bid = blockIdx.x;
  const int loss = bid >> 7, b = (bid >> 3) & 15, ch = bid & 7;
  const float* __restrict__ p = loss ? ls : hs;
  const float* __restrict__ s = loss ? lp : hp;
  const u16* __restrict__ Mp = M + (size_t)(loss ? 2 : 0)*NC_;
  const u16* __restrict__ Ms = M + (size_t)(loss ? 3 : 1)*NC_;
  const int t = threadIdx.x;
  const int c = t & 127;
  const int w = t >> 6, lane = t & 63, m = lane & 15, q = lane >> 4;
  const int n0 = ch * 1024;
  const size_t bOff = (size_t)b*NC_;
  float nsp = 0.f, nss = 0.f;
  f32x4 acc[8];
  #pragma unroll
  for (int j = 0; j < 8; ++j) acc[j] = 0.f;
  u32* PT32 = (u32*)PT;
  u32* ST32 = (u32*)ST;

  for (int st = 0; st < 32; ++st){
    const int row0 = n0 + st*32;
    #pragma unroll
    for (int it = 0; it < 4; ++it){
      const int idx = it*512 + t;
      const int k2 = idx >> 7;                 // 0..15, c stays t&127
      const int r = row0 + 2*k2;
      const size_t g = bOff + (size_t)r*C_ + c;
      const int mo = r*C_ + c;
      float v0 = p[g]       - bf2f(Mp[mo]);
      float v1 = p[g + C_]  - bf2f(Mp[mo + C_]);
      nsp += v0*v0 + v1*v1;
      PT32[c*(LDK/2) + k2] = (u32)f2bf(v0) | ((u32)f2bf(v1) << 16);
      float u0 = s[g]       - bf2f(Ms[mo]);
      float u1 = s[g + C_]  - bf2f(Ms[mo + C_]);
      nss += u0*u0 + u1*u1;
      ST32[c*(LDK/2) + k2] = (u32)f2bf(u0) | ((u32)f2bf(u1) << 16);
    }
    __syncthreads();
    // A[m][k] = centered p (c-major), B[k][n] = centered s; D = A*B
    bf16x8 a0 = *(const bf16x8*)(PT + (w*16 + m)*LDK + 8*q);
    #pragma unroll
    for (int j = 0; j < 8; ++j){
      bf16x8 bb = *(const bf16x8*)(ST + (j*16 + m)*LDK + 8*q);
      acc[j] = __builtin_amdgcn_mfma_f32_16x16x32_bf16(a0, bb, acc[j], 0, 0, 0);
    }
    __syncthreads();
  }

  float* out = slab + (size_t)bid*16384;
  #pragma unroll
  for (int j = 0; j < 8; ++j){
    const int rowB = w*16 + 4*q;               // C/D: row=(lane>>4)*4+reg
    const int colB = j*16 + m;                 //       col=lane&15
    #pragma unroll
    for (int r2 = 0; r2 < 4; ++r2)
      out[(rowB + r2)*C_ + colB] = acc[j][r2];
  }
  atomicAdd(&nsq[(loss*2 + 0)*2048 + b*C_ + c], nsp);
  atomicAdd(&nsq[(loss*2 + 1)*2048 + b*C_ + c], nss);
}

// ---------------- reduce slabs -> sum of corr^2 ----------------------------
__global__ __launch_bounds__(256) void k_diffred(const float* __restrict__ slab,
                                                 const float* __restrict__ nsq,
                                                 float* __restrict__ acc){
  __shared__ float sw[4];
  const int e = blockIdx.x*256 + threadIdx.x;    // < 524288
  const int loss = e >> 18;
  const int rem = e & 262143;
  const int b = rem >> 14;
  const int cd = rem & 16383;
  const int cc = cd >> 7, dd = cd & 127;
  float A = 0.f;
  const size_t base = (size_t)((loss*16 + b)*8)*16384 + cd;
  #pragma unroll
  for (int chn = 0; chn < 8; ++chn) A += slab[base + (size_t)chn*16384];
  float np_ = sqrtf(nsq[(loss*2 + 0)*2048 + b*C_ + cc]);
  float ns_ = sqrtf(nsq[(loss*2 + 1)*2048 + b*C_ + dd]);
  float corr = A / (fmaxf(np_, 1e-12f) * fmaxf(ns_, 1e-12f));
  float v = corr*corr;
  for (int o = 32; o; o >>= 1) v += __shfl_down(v, o);
  if ((threadIdx.x & 63) == 0) sw[threadIdx.x >> 6] = v;
  __syncthreads();
  if (threadIdx.x == 0) atomicAdd(&acc[3], sw[0]+sw[1]+sw[2]+sw[3]);
}

// ---------------- final composition ----------------------------------------
__global__ void k_final(const float* __restrict__ acc, const int* __restrict__ misc,
                        float* __restrict__ out){
  // 2*pearson_mean + (diff2+diff3) + 0.05*(recon_hf+recon_lf) + gnn
  out[0] = 2.0f*(acc[1]*(1.f/16.f))
         + acc[3]*(1.f/262144.f)
         + 0.05f*(acc[2]*(1.f/16777216.f))
         + acc[0]/(float)misc[2];
}

extern "C" void kernel_launch(void* const* d_in, const int* in_sizes, int n_in,
                              void* d_out, int out_size, void* d_ws, size_t ws_size,
                              hipStream_t stream){
  const float* hf  = (const float*)d_in[0];
  const float* lf  = (const float*)d_in[1];
  const float* hs  = (const float*)d_in[2];   // hf_shared
  const float* lsh = (const float*)d_in[3];   // lf_shared
  const float* hp  = (const float*)d_in[4];   // hf_private
  const float* lp  = (const float*)d_in[5];   // lf_private
  const float* rhf = (const float*)d_in[6];
  const float* rlf = (const float*)d_in[7];
  const float* sep = (const float*)d_in[8];
  // d_in[9] = noi_node: provably contributes 0 (mean-centering over batch of 1)
  const float* gt  = (const float*)d_in[10];

  // ws layout (float units). Total ~25.3 MB.
  float* ws    = (float*)d_ws;
  float* acc   = ws;                        // [0..16): gnn, pearson, recon, diff
  int*   misc  = (int*)(ws + 16);           // [16..32): pos0, pos1, index
  float* nsq   = ws + 32;                   // 4*16*128 = 8192 floats
  int*   order = (int*)(ws + 8224);         // 2*8192 ints
  u16*   M     = (u16*)(ws + 24608);        // 4*NC_ u16 (bf16 means)
  float* slab  = ws + 2121760;              // 256*16384 floats (GEMM partials)

  k_init<<<33, 256, 0, stream>>>(ws);
  k_sort<<<4096, 256, 0, stream>>>(gt, order, misc);
  k_index<<<1, 1, 0, stream>>>(misc);
  k_gnn<<<2048, 256, 0, stream>>>(sep, order, misc, acc);
  k_pearson<<<1, 1024, 0, stream>>>(hs, lsh, acc);
  k_recon<<<4096, 256, 0, stream>>>((const float4*)rhf, (const float4*)hf,
                                    (const float4*)rlf, (const float4*)lf, acc);
  k_mean<<<2048, 256, 0, stream>>>((const float4*)hs, (const float4*)hp,
                                   (const float4*)lsh, (const float4*)lp, M);
  k_gemm<<<256, 512, 0, stream>>>(hs, hp, lsh, lp, M, slab, nsq);
  k_diffred<<<2048, 256, 0, stream>>>(slab, nsq, acc);
  k_final<<<1, 1, 0, stream>>>(acc, misc, (float*)d_out);
}